// Round 6
// baseline (311.740 us; speedup 1.0000x reference)
//
#include <hip/hip_runtime.h>

// R6 = MEASUREMENT + FUSION ROUND.
//  - kF folded into kC via last-block ticket (bit-identical final sum).
//  - kC body repeated 4x internally (idempotent, memory-clobber forces real
//    reloads) so its dispatch (~4x kC) exceeds the 41 us poison fills and
//    surfaces in the rocprof top-5 WITH counters (VGPR/occupancy/VALUBusy).
//    kA precedes kC, so emb is L3-warm for all reps: kC ~= dur_rep / 4.

#define C_SEG 4096
#define E_CH 16
#define NE_EDGES 16384
#define P_PIX (1024 * 1024)
#define NCHUNK 32
#define CHUNK_PIX (P_PIX / NCHUNK)   // 32768
#define SCALE 262144.0f              // 2^18 fixed point
#define INV_SCALE (1.0f / 262144.0f)
#define KC_REPS 4

// ws layout (byte offsets):
//   0x000000  sums_part[16][32][4096] f32    8 MB
//   0x800000  cnt_part[32][4096]      f32  512 KB
//   0x880000  msum[4096][16]          f32  256 KB   (UNnormalized sums)
//   0x8C0000  inv_n[4096]             f32   16 KB
//   0x8C4000  part[1024]              f32    4 KB
//   0x8C5000  counter                 u32    4 B

__global__ __launch_bounds__(512) void kA(const float* __restrict__ emb,
                                          const int* __restrict__ seg,
                                          float* __restrict__ sums_part,
                                          float* __restrict__ cnt_part) {
    __shared__ int bins[C_SEG];  // 16 KB
    const int chunk = blockIdx.x;
    const int g = blockIdx.y;
    const int t = threadIdx.x;
    const int base = chunk * CHUNK_PIX;

    for (int i = t; i < C_SEG; i += 512) bins[i] = 0;
    __syncthreads();

    if (g == 16) {
        for (int it = 0; it < 16; ++it) {
            const int idx = base + (it * 512 + t) * 4;
            const int4 s4 = *(const int4*)(seg + idx);
            atomicAdd(&bins[s4.x], 1);
            atomicAdd(&bins[s4.y], 1);
            atomicAdd(&bins[s4.z], 1);
            atomicAdd(&bins[s4.w], 1);
        }
        __syncthreads();
        float* cd = cnt_part + (size_t)chunk * C_SEG;
        for (int i = t; i < C_SEG; i += 512) cd[i] = (float)bins[i];
    } else {
        const float* ec = emb + (size_t)g * P_PIX;
        for (int it = 0; it < 16; ++it) {
            const int idx = base + (it * 512 + t) * 4;
            const int4 s4 = *(const int4*)(seg + idx);
            const float4 v = *(const float4*)(ec + idx);
            atomicAdd(&bins[s4.x], __float2int_rn(v.x * SCALE));
            atomicAdd(&bins[s4.y], __float2int_rn(v.y * SCALE));
            atomicAdd(&bins[s4.z], __float2int_rn(v.z * SCALE));
            atomicAdd(&bins[s4.w], __float2int_rn(v.w * SCALE));
        }
        __syncthreads();
        float* dst = sums_part + ((size_t)g * NCHUNK + chunk) * C_SEG;
        for (int i = t; i < C_SEG; i += 512)
            dst[i] = (float)bins[i] * INV_SCALE;
    }
}

__global__ __launch_bounds__(256) void kB(const float* __restrict__ sums_part,
                                          const float* __restrict__ cnt_part,
                                          float* __restrict__ msum,
                                          float* __restrict__ inv_n,
                                          unsigned int* __restrict__ counter) {
    const int vb = blockIdx.x, t = threadIdx.x;
    if (vb == 0 && t == 0) counter[0] = 0u;  // arm kC's last-block ticket
    if (vb < 256) {
        const int c = vb >> 4;
        const int s = (vb & 15) * 256 + t;
        const float* src = sums_part + (size_t)c * NCHUNK * C_SEG + s;
        float acc = 0.0f;
#pragma unroll
        for (int k = 0; k < NCHUNK; ++k) acc += src[(size_t)k * C_SEG];
        msum[s * E_CH + c] = acc;  // UNnormalized
    } else {
        const int s = (vb - 256) * 256 + t;
        float acc = 0.0f;
#pragma unroll
        for (int k = 0; k < NCHUNK; ++k) acc += cnt_part[(size_t)k * C_SEG + s];
        inv_n[s] = 1.0f / fmaxf(acc, 1.0f);
    }
}

__global__ __launch_bounds__(256) void kC(const float* __restrict__ emb,
                                          const int* __restrict__ seg,
                                          const int* __restrict__ edges,
                                          const float* __restrict__ w,
                                          const float* __restrict__ msum,
                                          const float* __restrict__ inv_n,
                                          float* __restrict__ part,
                                          float* __restrict__ out,
                                          unsigned int* __restrict__ counter) {
    const int b = blockIdx.x, t = threadIdx.x;
    const int q = b * 256 + t;  // quad index, 262144 total
    __shared__ float red[4];

    for (int rep = 0; rep < KC_REPS; ++rep) {
        asm volatile("" ::: "memory");  // force true reloads each rep
        const int4 s4 = *(const int4*)(seg + q * 4);

        float mA[16], mB[16], mC[16], mD[16];
#pragma unroll
        for (int j = 0; j < 4; ++j) {
            ((float4*)mA)[j] = ((const float4*)(msum + s4.x * E_CH))[j];
            ((float4*)mB)[j] = ((const float4*)(msum + s4.y * E_CH))[j];
            ((float4*)mC)[j] = ((const float4*)(msum + s4.z * E_CH))[j];
            ((float4*)mD)[j] = ((const float4*)(msum + s4.w * E_CH))[j];
        }
        const float inx = inv_n[s4.x], iny = inv_n[s4.y];
        const float inz = inv_n[s4.z], inw = inv_n[s4.w];

        const float4* emb4 = (const float4*)emb;
        float4 e[16];
#pragma unroll
        for (int c = 0; c < 16; ++c) e[c] = emb4[(size_t)c * (P_PIX / 4) + q];

        float dx = 0.f, dy = 0.f, dz = 0.f, dw = 0.f;
#pragma unroll
        for (int c = 0; c < 16; ++c) {
            dx = fmaf(e[c].x, mA[c], dx);
            dy = fmaf(e[c].y, mB[c], dy);
            dz = fmaf(e[c].z, mC[c], dz);
            dw = fmaf(e[c].w, mD[c], dw);
        }

        float v = (fmaxf(0.5f - inx * dx, 0.0f) * inx +
                   fmaxf(0.5f - iny * dy, 0.0f) * iny +
                   fmaxf(0.5f - inz * dz, 0.0f) * inz +
                   fmaxf(0.5f - inw * dw, 0.0f) * inw) *
                  (1.0f / (float)C_SEG);

        if (t < 16) {  // 16 edges per block
            const int e2 = b * 16 + t;
            const int u = edges[e2];
            const int vv = edges[NE_EDGES + e2];
            const float4* mu = (const float4*)(msum + u * E_CH);
            const float4* mv = (const float4*)(msum + vv * E_CH);
            float dot = 0.0f;
#pragma unroll
            for (int j = 0; j < 4; ++j) {
                const float4 a = mu[j];
                const float4 bb = mv[j];
                dot = fmaf(a.x, bb.x, dot);
                dot = fmaf(a.y, bb.y, dot);
                dot = fmaf(a.z, bb.z, dot);
                dot = fmaf(a.w, bb.w, dot);
            }
            const float d = 1.0f - inv_n[u] * inv_n[vv] * dot;
            v += fmaxf(1.5f - d * w[e2], 0.0f) * (1.0f / (float)NE_EDGES);
        }

        for (int o = 32; o > 0; o >>= 1) v += __shfl_down(v, o, 64);
        if ((t & 63) == 0) red[t >> 6] = v;
        __syncthreads();
        if (t == 0) part[b] = red[0] + red[1] + red[2] + red[3];
        __syncthreads();  // red[] reused next rep
    }

    // ---- fused kF: last block sums part[] in index order (== old kF) ----
    __threadfence();
    __shared__ unsigned int tick;
    if (t == 0) tick = atomicAdd(counter, 1u);
    __syncthreads();
    if (tick == 1023u) {
        __threadfence();
        float v = 0.0f;
        for (int i = t; i < 1024; i += 256) v += part[i];
        for (int o = 32; o > 0; o >>= 1) v += __shfl_down(v, o, 64);
        if ((t & 63) == 0) red[t >> 6] = v;
        __syncthreads();
        if (t == 0) {
            out[0] = red[0] + red[1] + red[2] + red[3];
            counter[0] = 0u;
        }
    }
}

extern "C" void kernel_launch(void* const* d_in, const int* in_sizes, int n_in,
                              void* d_out, int out_size, void* d_ws,
                              size_t ws_size, hipStream_t stream) {
    const float* emb = (const float*)d_in[0];      // (1,16,1024,1024) fp32
    const float* weights = (const float*)d_in[1];  // (16384,) fp32
    const int* seg = (const int*)d_in[2];          // (1,1,1024,1024) int32
    const int* edges = (const int*)d_in[3];        // (2,16384) int32
    float* out = (float*)d_out;

    char* ws = (char*)d_ws;
    float* sums_part = (float*)(ws);
    float* cnt_part = (float*)(ws + 0x800000);
    float* msum = (float*)(ws + 0x880000);
    float* invn = (float*)(ws + 0x8C0000);
    float* part = (float*)(ws + 0x8C4000);
    unsigned int* counter = (unsigned int*)(ws + 0x8C5000);

    dim3 gA(NCHUNK, 17);
    kA<<<gA, 512, 0, stream>>>(emb, seg, sums_part, cnt_part);
    kB<<<272, 256, 0, stream>>>(sums_part, cnt_part, msum, invn, counter);
    kC<<<1024, 256, 0, stream>>>(emb, seg, edges, weights, msum, invn, part, out, counter);
}

// Round 7
// 131.021 us; speedup vs baseline: 2.3793x; 2.3793x over previous
//
#include <hip/hip_runtime.h>

// R7: kC redesigned around the R6 counter evidence (VALUBusy 1.7%, HBM 8%,
// occupancy 25% => latency-bound on 5.2M divergent mean-gathers). The mean
// table (4096 segs x 8 ch f32 = 128 KB) is staged in LDS in two channel
// halves; per-pixel gathers become ds_read_b128. Per-pixel FMA order is
// unchanged -> per-pixel dots bit-identical; emb streams stay coalesced.
// kA unchanged (measured at its 12 us traffic floor in R5). kF stays fused
// into kC via the R6 last-block ticket.

#define C_SEG 4096
#define E_CH 16
#define NE_EDGES 16384
#define P_PIX (1024 * 1024)
#define NCHUNK 32
#define CHUNK_PIX (P_PIX / NCHUNK)   // 32768
#define SCALE 262144.0f              // 2^18 fixed point
#define INV_SCALE (1.0f / 262144.0f)

// ws layout (byte offsets):
//   0x000000  sums_part[16][32][4096] f32    8 MB
//   0x800000  cnt_part[32][4096]      f32  512 KB
//   0x880000  mh[2][4096][8]          f32  256 KB  (UNnormalized sums, two
//                                                   channel-half tables)
//   0x8C0000  inv_n[4096]             f32   16 KB
//   0x8C4000  part[256]               f32    1 KB
//   0x8C5000  counter                 u32    4 B

__global__ __launch_bounds__(512) void kA(const float* __restrict__ emb,
                                          const int* __restrict__ seg,
                                          float* __restrict__ sums_part,
                                          float* __restrict__ cnt_part) {
    __shared__ int bins[C_SEG];  // 16 KB
    const int chunk = blockIdx.x;
    const int g = blockIdx.y;
    const int t = threadIdx.x;
    const int base = chunk * CHUNK_PIX;

    for (int i = t; i < C_SEG; i += 512) bins[i] = 0;
    __syncthreads();

    if (g == 16) {
        for (int it = 0; it < 16; ++it) {
            const int idx = base + (it * 512 + t) * 4;
            const int4 s4 = *(const int4*)(seg + idx);
            atomicAdd(&bins[s4.x], 1);
            atomicAdd(&bins[s4.y], 1);
            atomicAdd(&bins[s4.z], 1);
            atomicAdd(&bins[s4.w], 1);
        }
        __syncthreads();
        float* cd = cnt_part + (size_t)chunk * C_SEG;
        for (int i = t; i < C_SEG; i += 512) cd[i] = (float)bins[i];
    } else {
        const float* ec = emb + (size_t)g * P_PIX;
        for (int it = 0; it < 16; ++it) {
            const int idx = base + (it * 512 + t) * 4;
            const int4 s4 = *(const int4*)(seg + idx);
            const float4 v = *(const float4*)(ec + idx);
            atomicAdd(&bins[s4.x], __float2int_rn(v.x * SCALE));
            atomicAdd(&bins[s4.y], __float2int_rn(v.y * SCALE));
            atomicAdd(&bins[s4.z], __float2int_rn(v.z * SCALE));
            atomicAdd(&bins[s4.w], __float2int_rn(v.w * SCALE));
        }
        __syncthreads();
        float* dst = sums_part + ((size_t)g * NCHUNK + chunk) * C_SEG;
        for (int i = t; i < C_SEG; i += 512)
            dst[i] = (float)bins[i] * INV_SCALE;
    }
}

// ---------------------------------------------------------------------------
// kB: merge chunk partials into the two half-tables mh[h][s][c] (c = ch&7,
// h = ch>>3) so kC's LDS staging is a straight coalesced copy. Also inv_n,
// and arms kC's last-block ticket counter.
// ---------------------------------------------------------------------------
__global__ __launch_bounds__(256) void kB(const float* __restrict__ sums_part,
                                          const float* __restrict__ cnt_part,
                                          float* __restrict__ mh,
                                          float* __restrict__ inv_n,
                                          unsigned int* __restrict__ counter) {
    const int vb = blockIdx.x, t = threadIdx.x;
    if (vb == 0 && t == 0) counter[0] = 0u;
    if (vb < 256) {
        const int c = vb >> 4;
        const int s = (vb & 15) * 256 + t;
        const float* src = sums_part + (size_t)c * NCHUNK * C_SEG + s;
        float acc = 0.0f;
#pragma unroll
        for (int k = 0; k < NCHUNK; ++k) acc += src[(size_t)k * C_SEG];
        mh[(size_t)(c >> 3) * (C_SEG * 8) + s * 8 + (c & 7)] = acc;
    } else {
        const int s = (vb - 256) * 256 + t;
        float acc = 0.0f;
#pragma unroll
        for (int k = 0; k < NCHUNK; ++k) acc += cnt_part[(size_t)k * C_SEG + s];
        inv_n[s] = 1.0f / fmaxf(acc, 1.0f);
    }
}

// ---------------------------------------------------------------------------
// kC: 256 blocks x 1024 threads, 1 quad (4 px)/thread. Two phases: stage
// mh half into 128 KB LDS -> emb streams (coalesced, issued first) + mean
// reads from LDS (2x ds_read_b128 per px) -> partial dots; barrier;
// restage; finish. Same per-pixel fmaf order as the R0 kernel. Edges
// (64/block, t<64) gather from mh in L2 (16K edges, negligible). kF fused
// via last-block ticket.
// ---------------------------------------------------------------------------
__global__ __launch_bounds__(1024) void kC(const float* __restrict__ emb,
                                           const int* __restrict__ seg,
                                           const int* __restrict__ edges,
                                           const float* __restrict__ w,
                                           const float* __restrict__ mh,
                                           const float* __restrict__ inv_n,
                                           float* __restrict__ part,
                                           float* __restrict__ out,
                                           unsigned int* __restrict__ counter) {
    __shared__ float mtab[C_SEG * 8];  // 128 KB
    __shared__ float red[16];
    __shared__ unsigned int tick;
    const int b = blockIdx.x, t = threadIdx.x;
    const int q = b * 1024 + t;  // quad index, 262144 total
    const int4 s4 = *(const int4*)(seg + q * 4);
    const float inx = inv_n[s4.x], iny = inv_n[s4.y];
    const float inz = inv_n[s4.z], inw = inv_n[s4.w];
    const float4* emb4 = (const float4*)emb;

    // ---- stage half 0 (channels 0..7): coalesced 128 KB copy ----
    {
        const float4* src = (const float4*)mh;
        float4* dst = (float4*)mtab;
#pragma unroll
        for (int i = 0; i < 8; ++i) dst[t + i * 1024] = src[t + i * 1024];
    }
    __syncthreads();

    float dx = 0.f, dy = 0.f, dz = 0.f, dw = 0.f;

    // ---- phase 0: channels 0..7 ----
    {
        float4 e[8];
#pragma unroll
        for (int c = 0; c < 8; ++c) e[c] = emb4[(size_t)c * (P_PIX / 4) + q];
        float mA[8], mB[8], mC[8], mD[8];
        const float4* a4 = (const float4*)(mtab + s4.x * 8);
        const float4* b4 = (const float4*)(mtab + s4.y * 8);
        const float4* c4 = (const float4*)(mtab + s4.z * 8);
        const float4* d4 = (const float4*)(mtab + s4.w * 8);
#pragma unroll
        for (int j = 0; j < 2; ++j) {
            ((float4*)mA)[j] = a4[j];
            ((float4*)mB)[j] = b4[j];
            ((float4*)mC)[j] = c4[j];
            ((float4*)mD)[j] = d4[j];
        }
#pragma unroll
        for (int c = 0; c < 8; ++c) {
            dx = fmaf(e[c].x, mA[c], dx);
            dy = fmaf(e[c].y, mB[c], dy);
            dz = fmaf(e[c].z, mC[c], dz);
            dw = fmaf(e[c].w, mD[c], dw);
        }
    }
    __syncthreads();

    // ---- restage half 1 (channels 8..15) ----
    {
        const float4* src = (const float4*)(mh + (size_t)C_SEG * 8);
        float4* dst = (float4*)mtab;
#pragma unroll
        for (int i = 0; i < 8; ++i) dst[t + i * 1024] = src[t + i * 1024];
    }
    __syncthreads();

    // ---- phase 1: channels 8..15 (same accumulators, same fma order) ----
    {
        float4 e[8];
#pragma unroll
        for (int c = 0; c < 8; ++c) e[c] = emb4[(size_t)(c + 8) * (P_PIX / 4) + q];
        float mA[8], mB[8], mC[8], mD[8];
        const float4* a4 = (const float4*)(mtab + s4.x * 8);
        const float4* b4 = (const float4*)(mtab + s4.y * 8);
        const float4* c4 = (const float4*)(mtab + s4.z * 8);
        const float4* d4 = (const float4*)(mtab + s4.w * 8);
#pragma unroll
        for (int j = 0; j < 2; ++j) {
            ((float4*)mA)[j] = a4[j];
            ((float4*)mB)[j] = b4[j];
            ((float4*)mC)[j] = c4[j];
            ((float4*)mD)[j] = d4[j];
        }
#pragma unroll
        for (int c = 0; c < 8; ++c) {
            dx = fmaf(e[c].x, mA[c], dx);
            dy = fmaf(e[c].y, mB[c], dy);
            dz = fmaf(e[c].z, mC[c], dz);
            dw = fmaf(e[c].w, mD[c], dw);
        }
    }

    float v = (fmaxf(0.5f - inx * dx, 0.0f) * inx +
               fmaxf(0.5f - iny * dy, 0.0f) * iny +
               fmaxf(0.5f - inz * dz, 0.0f) * inz +
               fmaxf(0.5f - inw * dw, 0.0f) * inw) *
              (1.0f / (float)C_SEG);

    if (t < 64) {  // 64 edges per block, gathers from L2-resident mh (256 KB)
        const int e2 = b * 64 + t;
        const int u = edges[e2];
        const int vv = edges[NE_EDGES + e2];
        const float4* mu0 = (const float4*)(mh + u * 8);
        const float4* mv0 = (const float4*)(mh + vv * 8);
        const float4* mu1 = (const float4*)(mh + (size_t)C_SEG * 8 + u * 8);
        const float4* mv1 = (const float4*)(mh + (size_t)C_SEG * 8 + vv * 8);
        float dot = 0.0f;
#pragma unroll
        for (int j = 0; j < 2; ++j) {
            const float4 a = mu0[j];
            const float4 bb = mv0[j];
            dot = fmaf(a.x, bb.x, dot);
            dot = fmaf(a.y, bb.y, dot);
            dot = fmaf(a.z, bb.z, dot);
            dot = fmaf(a.w, bb.w, dot);
        }
#pragma unroll
        for (int j = 0; j < 2; ++j) {
            const float4 a = mu1[j];
            const float4 bb = mv1[j];
            dot = fmaf(a.x, bb.x, dot);
            dot = fmaf(a.y, bb.y, dot);
            dot = fmaf(a.z, bb.z, dot);
            dot = fmaf(a.w, bb.w, dot);
        }
        const float d = 1.0f - inv_n[u] * inv_n[vv] * dot;
        v += fmaxf(1.5f - d * w[e2], 0.0f) * (1.0f / (float)NE_EDGES);
    }

    // ---- block reduction (16 waves) ----
    for (int o = 32; o > 0; o >>= 1) v += __shfl_down(v, o, 64);
    if ((t & 63) == 0) red[t >> 6] = v;
    __syncthreads();
    if (t == 0) {
        float s = 0.0f;
#pragma unroll
        for (int i = 0; i < 16; ++i) s += red[i];
        part[b] = s;
        __threadfence();
        tick = atomicAdd(counter, 1u);
    }
    __syncthreads();

    // ---- fused kF: last of 256 blocks sums part[] in index order ----
    if (tick == 255u) {
        __threadfence();
        float v2 = (t < 256) ? part[t] : 0.0f;
        for (int o = 32; o > 0; o >>= 1) v2 += __shfl_down(v2, o, 64);
        if ((t & 63) == 0) red[t >> 6] = v2;
        __syncthreads();
        if (t == 0) {
            float s = 0.0f;
#pragma unroll
            for (int i = 0; i < 16; ++i) s += red[i];
            out[0] = s;
            counter[0] = 0u;
        }
    }
}

extern "C" void kernel_launch(void* const* d_in, const int* in_sizes, int n_in,
                              void* d_out, int out_size, void* d_ws,
                              size_t ws_size, hipStream_t stream) {
    const float* emb = (const float*)d_in[0];      // (1,16,1024,1024) fp32
    const float* weights = (const float*)d_in[1];  // (16384,) fp32
    const int* seg = (const int*)d_in[2];          // (1,1,1024,1024) int32
    const int* edges = (const int*)d_in[3];        // (2,16384) int32
    float* out = (float*)d_out;

    char* ws = (char*)d_ws;
    float* sums_part = (float*)(ws);
    float* cnt_part = (float*)(ws + 0x800000);
    float* mh = (float*)(ws + 0x880000);
    float* invn = (float*)(ws + 0x8C0000);
    float* part = (float*)(ws + 0x8C4000);
    unsigned int* counter = (unsigned int*)(ws + 0x8C5000);

    dim3 gA(NCHUNK, 17);
    kA<<<gA, 512, 0, stream>>>(emb, seg, sums_part, cnt_part);
    kB<<<272, 256, 0, stream>>>(sums_part, cnt_part, mh, invn, counter);
    kC<<<256, 1024, 0, stream>>>(emb, seg, edges, weights, mh, invn, part, out, counter);
}